// Round 14
// baseline (188.036 us; speedup 1.0000x reference)
//
#include <hip/hip_runtime.h>
#include <hip/hip_bf16.h>
#include <hip/hip_fp16.h>

typedef _Float16 half8_t  __attribute__((ext_vector_type(8)));
typedef short    short8_t __attribute__((ext_vector_type(8)));
typedef short    short4_t __attribute__((ext_vector_type(4)));
typedef float    f32x4    __attribute__((ext_vector_type(4)));

#define LOG2E 1.44269504088896f

__device__ __forceinline__ unsigned pack_bf16_2(float lo, float hi) {
  float2 f2; f2.x = lo; f2.y = hi;
  __hip_bfloat162 h2 = __float22bfloat162_rn(f2);
  return *reinterpret_cast<unsigned*>(&h2);
}

// ---------------------------------------------------------------------------
// Kernel 1 (v8, unchanged from R13): MFMA prep. One block = 64 positions.
// C = x[64 x 64] @ W[64 x 80] via 16x16x32 f16 MFMA; epilogue writes f
// (key-permuted slots), g (x log2e), vT4 ([b][kblock][ch][r] bf16).
// ---------------------------------------------------------------------------
__global__ __launch_bounds__(256) void prep_kernel(
    const float* __restrict__ x,
    const float* __restrict__ Wf, const float* __restrict__ bf,
    const float* __restrict__ Wg, const float* __restrict__ bg,
    const float* __restrict__ Wh, const float* __restrict__ bh,
    _Float16* __restrict__ fh, _Float16* __restrict__ gh,
    unsigned short* __restrict__ vT)
{
  __shared__ _Float16 WtT[80 * 72];   // [ch][c], stride 72
  __shared__ float ball[80];
  const int t = threadIdx.x;

  for (int i = t; i < 512; i += 256) {
    int c = i >> 3, d = i & 7;
    WtT[d * 72 + c]       = (_Float16)Wf[i];
    WtT[(8 + d) * 72 + c] = (_Float16)(Wg[i] * LOG2E);
  }
  for (int i = t; i < 4096; i += 256) {
    int c = i >> 6, ch = i & 63;
    WtT[(16 + ch) * 72 + c] = (_Float16)Wh[i];
  }
  if (t < 80) ball[t] = (t < 8) ? bf[t] : (t < 16) ? bg[t - 8] * LOG2E : bh[t - 16];
  __syncthreads();

  const int lane = t & 63, w = t >> 6;
  const int quad = lane >> 4, l15 = lane & 15;
  const int p0 = blockIdx.x * 64;
  const int row = p0 + w * 16 + l15;

  const float* xr = x + (size_t)row * 64 + quad * 8;
  float4 xa = *(const float4*)(xr);
  float4 xb = *(const float4*)(xr + 4);
  float4 xc = *(const float4*)(xr + 32);
  float4 xd = *(const float4*)(xr + 36);
  half8_t a0, a1;
  a0[0]=(_Float16)xa.x; a0[1]=(_Float16)xa.y; a0[2]=(_Float16)xa.z; a0[3]=(_Float16)xa.w;
  a0[4]=(_Float16)xb.x; a0[5]=(_Float16)xb.y; a0[6]=(_Float16)xb.z; a0[7]=(_Float16)xb.w;
  a1[0]=(_Float16)xc.x; a1[1]=(_Float16)xc.y; a1[2]=(_Float16)xc.z; a1[3]=(_Float16)xc.w;
  a1[4]=(_Float16)xd.x; a1[5]=(_Float16)xd.y; a1[6]=(_Float16)xd.z; a1[7]=(_Float16)xd.w;

  const f32x4 zc = {0.f, 0.f, 0.f, 0.f};
  const int b     = p0 >> 12;
  const int nbase = (p0 & 4095) + w * 16 + quad * 4;
  const int kblock = nbase >> 5;
  const int r0     = nbase & 31;
  const int q8 = r0 >> 3, j8 = r0 & 7;
  const int slot0 = (j8 < 4) ? (q8 * 4 + j8) : (16 + q8 * 4 + (j8 - 4));
  const size_t fbase_out = ((size_t)b * 4096 + (kblock << 5) + slot0) * 8;
  const size_t gbase_out = ((size_t)p0 + w * 16 + quad * 4) * 8;
  const size_t vbase_out = (((size_t)b * 128 + kblock) << 11) + r0;

#pragma unroll
  for (int nt = 0; nt < 5; nt++) {
    const int ch0 = nt * 16 + l15;
    const _Float16* wt = &WtT[ch0 * 72 + quad * 8];
    half8_t b0 = *(const half8_t*)(wt);
    half8_t b1 = *(const half8_t*)(wt + 32);
    f32x4 d = __builtin_amdgcn_mfma_f32_16x16x32_f16(a0, b0, zc, 0, 0, 0);
    d = __builtin_amdgcn_mfma_f32_16x16x32_f16(a1, b1, d, 0, 0, 0);
    const float bias = ball[ch0];
    if (nt == 0) {
      if (l15 < 8) {
#pragma unroll
        for (int reg = 0; reg < 4; reg++)
          fh[fbase_out + (size_t)reg * 8 + l15] = (_Float16)(d[reg] + bias);
      } else {
#pragma unroll
        for (int reg = 0; reg < 4; reg++)
          gh[gbase_out + (size_t)reg * 8 + (l15 - 8)] = (_Float16)(d[reg] + bias);
      }
    } else {
      const int vch = ch0 - 16;
      union { unsigned u[2]; short4_t s; } pk;
      pk.u[0] = pack_bf16_2(d[0] + bias, d[1] + bias);
      pk.u[1] = pack_bf16_2(d[2] + bias, d[3] + bias);
      *(short4_t*)(vT + vbase_out + (size_t)vch * 32) = pk.s;
    }
  }
}

// ---------------------------------------------------------------------------
// Kernel 2 (v14): 64-query blocks, 16 WAVES (1024 thr) — same minimal key
// traffic as R12/R13 (147 MB) but 4 waves/SIMD instead of 2 (R13 ran 1
// block/CU x 8 waves = 2/SIMD: everything exposed). Wave w covers 256 keys.
// Combine: 15 partials through 65,280 B LDS. __launch_bounds__(1024,4):
// VGPR cap 128 (R13 used 88 — headroom, no squeeze/spill).
// ---------------------------------------------------------------------------
__global__ __launch_bounds__(1024, 4) void attn_kernel(
    const _Float16* __restrict__ fh,        // [B][N][8] f16, key-permuted slots
    const _Float16* __restrict__ gh,        // [B][N][8] f16 (x log2e)
    const unsigned short* __restrict__ vT,  // [b][kblock][ch][r] bf16
    float* __restrict__ out)                // [B][N][64] f32
{
  const int N    = 4096;
  const int lane = threadIdx.x & 63;
  const int w    = threadIdx.x >> 6;       // 0..15 = key range
  const int quad = lane >> 4;
  const int l15  = lane & 15;

  __shared__ float red[15][64][17];        // 65,280 B

  const int xcd = blockIdx.x & 7;
  const int b   = xcd >> 1;
  const int qg  = ((blockIdx.x >> 3) << 1) + (xcd & 1);  // 0..63
  const int q0  = qg * 64;
  const int kbase = w * 256;

  const _Float16* fbase = fh + (size_t)b * N * 8;
  const _Float16* gbase = gh + (size_t)b * N * 8;
  const short*    vbat  = (const short*)vT + (size_t)b * 262144 + (l15 << 5) + (quad << 3);

  half8_t gfrag[4] = {{}, {}, {}, {}};
  if (quad == 0) {
#pragma unroll
    for (int tt = 0; tt < 4; tt++)
      gfrag[tt] = *(const half8_t*)(gbase + (size_t)(q0 + tt * 16 + l15) * 8);
  }

  const f32x4 zc = {0.f, 0.f, 0.f, 0.f};
  f32x4 acc[4][4];
  f32x4 acc4[4];
#pragma unroll
  for (int tt = 0; tt < 4; tt++) {
    acc4[tt] = zc;
#pragma unroll
    for (int ct = 0; ct < 4; ct++) acc[tt][ct] = zc;
  }

  short8_t ones8;
#pragma unroll
  for (int i = 0; i < 8; i++) ones8[i] = (short)0x3F80;

  // ping-pong load buffers
  half8_t  fa0 = {}, fa1 = {}, fb0 = {}, fb1 = {};
  short8_t va0, va1, va2, va3, vb0, vb1, vb2, vb3;

  {
    const int k0 = kbase;
    if (quad == 0) {
      fa0 = *(const half8_t*)(fbase + (size_t)(k0 + l15) * 8);
      fa1 = *(const half8_t*)(fbase + (size_t)(k0 + 16 + l15) * 8);
    }
    const short* vk = vbat + ((size_t)(k0 >> 5) << 11);
    va0 = *(const short8_t*)(vk);
    va1 = *(const short8_t*)(vk + 512);
    va2 = *(const short8_t*)(vk + 1024);
    va3 = *(const short8_t*)(vk + 1536);
  }

  auto compute4 = [&](const half8_t& f0, const half8_t& f1,
                      const short8_t& v0, const short8_t& v1,
                      const short8_t& v2, const short8_t& v3) {
#pragma unroll
    for (int tt = 0; tt < 4; tt++) {
      f32x4 s0 = __builtin_amdgcn_mfma_f32_16x16x32_f16(f0, gfrag[tt], zc, 0, 0, 0);
      f32x4 s1 = __builtin_amdgcn_mfma_f32_16x16x32_f16(f1, gfrag[tt], zc, 0, 0, 0);
      float p00 = __builtin_amdgcn_exp2f(s0[0]), p01 = __builtin_amdgcn_exp2f(s0[1]);
      float p02 = __builtin_amdgcn_exp2f(s0[2]), p03 = __builtin_amdgcn_exp2f(s0[3]);
      float p10 = __builtin_amdgcn_exp2f(s1[0]), p11 = __builtin_amdgcn_exp2f(s1[1]);
      float p12 = __builtin_amdgcn_exp2f(s1[2]), p13 = __builtin_amdgcn_exp2f(s1[3]);
      union { unsigned u[4]; short8_t v; } pu;
      pu.u[0] = pack_bf16_2(p00, p01);
      pu.u[1] = pack_bf16_2(p02, p03);
      pu.u[2] = pack_bf16_2(p10, p11);
      pu.u[3] = pack_bf16_2(p12, p13);
      short8_t pfrag = pu.v;
      acc[tt][0] = __builtin_amdgcn_mfma_f32_16x16x32_bf16(v0, pfrag, acc[tt][0], 0, 0, 0);
      acc[tt][1] = __builtin_amdgcn_mfma_f32_16x16x32_bf16(v1, pfrag, acc[tt][1], 0, 0, 0);
      acc[tt][2] = __builtin_amdgcn_mfma_f32_16x16x32_bf16(v2, pfrag, acc[tt][2], 0, 0, 0);
      acc[tt][3] = __builtin_amdgcn_mfma_f32_16x16x32_bf16(v3, pfrag, acc[tt][3], 0, 0, 0);
      acc4[tt]   = __builtin_amdgcn_mfma_f32_16x16x32_bf16(ones8, pfrag, acc4[tt], 0, 0, 0);
    }
  };

#pragma unroll 1
  for (int cc = 0; cc < 8; cc += 2) {
    {
      const int k1 = kbase + (cc + 1) * 32;
      if (quad == 0) {
        fb0 = *(const half8_t*)(fbase + (size_t)(k1 + l15) * 8);
        fb1 = *(const half8_t*)(fbase + (size_t)(k1 + 16 + l15) * 8);
      }
      const short* vk = vbat + ((size_t)(k1 >> 5) << 11);
      vb0 = *(const short8_t*)(vk);
      vb1 = *(const short8_t*)(vk + 512);
      vb2 = *(const short8_t*)(vk + 1024);
      vb3 = *(const short8_t*)(vk + 1536);
    }
    compute4(fa0, fa1, va0, va1, va2, va3);
    if (cc + 2 < 8) {
      const int k2 = kbase + (cc + 2) * 32;
      if (quad == 0) {
        fa0 = *(const half8_t*)(fbase + (size_t)(k2 + l15) * 8);
        fa1 = *(const half8_t*)(fbase + (size_t)(k2 + 16 + l15) * 8);
      }
      const short* vk = vbat + ((size_t)(k2 >> 5) << 11);
      va0 = *(const short8_t*)(vk);
      va1 = *(const short8_t*)(vk + 512);
      va2 = *(const short8_t*)(vk + 1024);
      va3 = *(const short8_t*)(vk + 1536);
    }
    compute4(fb0, fb1, vb0, vb1, vb2, vb3);
  }

  // ---- cross-wave combine: 4 sequential phases, 15 partials each ----
#pragma unroll 1
  for (int tt = 0; tt < 4; tt++) {
    if (w > 0) {
      float* p = &red[w - 1][lane][0];
#pragma unroll
      for (int ct = 0; ct < 4; ct++)
#pragma unroll
        for (int reg = 0; reg < 4; reg++) p[ct * 4 + reg] = acc[tt][ct][reg];
      p[16] = acc4[tt][0];
    }
    __syncthreads();
    if (w == 0) {
      f32x4 a0 = acc[tt][0], a1 = acc[tt][1], a2 = acc[tt][2], a3 = acc[tt][3];
      float lv = acc4[tt][0];
#pragma unroll
      for (int ww = 0; ww < 15; ww++) {
        const float* p = &red[ww][lane][0];
#pragma unroll
        for (int reg = 0; reg < 4; reg++) {
          a0[reg] += p[0 + reg];
          a1[reg] += p[4 + reg];
          a2[reg] += p[8 + reg];
          a3[reg] += p[12 + reg];
        }
        lv += p[16];
      }
      const float inv = 1.0f / lv;
      float* ob = out + ((size_t)b * N + q0 + tt * 16 + l15) * 64 + (quad << 2);
      *(f32x4*)(ob)      = a0 * inv;
      *(f32x4*)(ob + 16) = a1 * inv;
      *(f32x4*)(ob + 32) = a2 * inv;
      *(f32x4*)(ob + 48) = a3 * inv;
    }
    __syncthreads();
  }
}

// ---------------------------------------------------------------------------
extern "C" void kernel_launch(void* const* d_in, const int* in_sizes, int n_in,
                              void* d_out, int out_size, void* d_ws, size_t ws_size,
                              hipStream_t stream) {
  const float* x  = (const float*)d_in[0];
  const float* Wf = (const float*)d_in[1];
  const float* bf = (const float*)d_in[2];
  const float* Wg = (const float*)d_in[3];
  const float* bg = (const float*)d_in[4];
  const float* Wh = (const float*)d_in[5];
  const float* bh = (const float*)d_in[6];
  float* out = (float*)d_out;

  char* ws = (char*)d_ws;
  _Float16* fh = (_Float16*)ws;                        // 256 KB
  _Float16* gh = (_Float16*)(ws + 262144);             // 256 KB
  unsigned short* vT = (unsigned short*)(ws + 524288); // 2 MB

  prep_kernel<<<256, 256, 0, stream>>>(x, Wf, bf, Wg, bg, Wh, bh, fh, gh, vT);
  attn_kernel<<<256, 1024, 0, stream>>>(fh, gh, vT, out);
}

// Round 15
// 187.612 us; speedup vs baseline: 1.0023x; 1.0023x over previous
//
#include <hip/hip_runtime.h>
#include <hip/hip_bf16.h>
#include <hip/hip_fp16.h>

typedef _Float16 half8_t  __attribute__((ext_vector_type(8)));
typedef short    short8_t __attribute__((ext_vector_type(8)));
typedef short    short4_t __attribute__((ext_vector_type(4)));
typedef float    f32x4    __attribute__((ext_vector_type(4)));

#define LOG2E 1.44269504088896f

__device__ __forceinline__ unsigned pack_bf16_2(float lo, float hi) {
  float2 f2; f2.x = lo; f2.y = hi;
  __hip_bfloat162 h2 = __float22bfloat162_rn(f2);
  return *reinterpret_cast<unsigned*>(&h2);
}

// ---------------------------------------------------------------------------
// Kernel 1 (v8, unchanged): MFMA prep. One block = 64 positions.
// C = x[64 x 64] @ W[64 x 80] via 16x16x32 f16 MFMA; epilogue writes f
// (key-permuted slots), g (x log2e), vT4 ([b][kblock][ch][r] bf16).
// ---------------------------------------------------------------------------
__global__ __launch_bounds__(256) void prep_kernel(
    const float* __restrict__ x,
    const float* __restrict__ Wf, const float* __restrict__ bf,
    const float* __restrict__ Wg, const float* __restrict__ bg,
    const float* __restrict__ Wh, const float* __restrict__ bh,
    _Float16* __restrict__ fh, _Float16* __restrict__ gh,
    unsigned short* __restrict__ vT)
{
  __shared__ _Float16 WtT[80 * 72];   // [ch][c], stride 72
  __shared__ float ball[80];
  const int t = threadIdx.x;

  for (int i = t; i < 512; i += 256) {
    int c = i >> 3, d = i & 7;
    WtT[d * 72 + c]       = (_Float16)Wf[i];
    WtT[(8 + d) * 72 + c] = (_Float16)(Wg[i] * LOG2E);
  }
  for (int i = t; i < 4096; i += 256) {
    int c = i >> 6, ch = i & 63;
    WtT[(16 + ch) * 72 + c] = (_Float16)Wh[i];
  }
  if (t < 80) ball[t] = (t < 8) ? bf[t] : (t < 16) ? bg[t - 8] * LOG2E : bh[t - 16];
  __syncthreads();

  const int lane = t & 63, w = t >> 6;
  const int quad = lane >> 4, l15 = lane & 15;
  const int p0 = blockIdx.x * 64;
  const int row = p0 + w * 16 + l15;

  const float* xr = x + (size_t)row * 64 + quad * 8;
  float4 xa = *(const float4*)(xr);
  float4 xb = *(const float4*)(xr + 4);
  float4 xc = *(const float4*)(xr + 32);
  float4 xd = *(const float4*)(xr + 36);
  half8_t a0, a1;
  a0[0]=(_Float16)xa.x; a0[1]=(_Float16)xa.y; a0[2]=(_Float16)xa.z; a0[3]=(_Float16)xa.w;
  a0[4]=(_Float16)xb.x; a0[5]=(_Float16)xb.y; a0[6]=(_Float16)xb.z; a0[7]=(_Float16)xb.w;
  a1[0]=(_Float16)xc.x; a1[1]=(_Float16)xc.y; a1[2]=(_Float16)xc.z; a1[3]=(_Float16)xc.w;
  a1[4]=(_Float16)xd.x; a1[5]=(_Float16)xd.y; a1[6]=(_Float16)xd.z; a1[7]=(_Float16)xd.w;

  const f32x4 zc = {0.f, 0.f, 0.f, 0.f};
  const int b     = p0 >> 12;
  const int nbase = (p0 & 4095) + w * 16 + quad * 4;
  const int kblock = nbase >> 5;
  const int r0     = nbase & 31;
  const int q8 = r0 >> 3, j8 = r0 & 7;
  const int slot0 = (j8 < 4) ? (q8 * 4 + j8) : (16 + q8 * 4 + (j8 - 4));
  const size_t fbase_out = ((size_t)b * 4096 + (kblock << 5) + slot0) * 8;
  const size_t gbase_out = ((size_t)p0 + w * 16 + quad * 4) * 8;
  const size_t vbase_out = (((size_t)b * 128 + kblock) << 11) + r0;

#pragma unroll
  for (int nt = 0; nt < 5; nt++) {
    const int ch0 = nt * 16 + l15;
    const _Float16* wt = &WtT[ch0 * 72 + quad * 8];
    half8_t b0 = *(const half8_t*)(wt);
    half8_t b1 = *(const half8_t*)(wt + 32);
    f32x4 d = __builtin_amdgcn_mfma_f32_16x16x32_f16(a0, b0, zc, 0, 0, 0);
    d = __builtin_amdgcn_mfma_f32_16x16x32_f16(a1, b1, d, 0, 0, 0);
    const float bias = ball[ch0];
    if (nt == 0) {
      if (l15 < 8) {
#pragma unroll
        for (int reg = 0; reg < 4; reg++)
          fh[fbase_out + (size_t)reg * 8 + l15] = (_Float16)(d[reg] + bias);
      } else {
#pragma unroll
        for (int reg = 0; reg < 4; reg++)
          gh[gbase_out + (size_t)reg * 8 + (l15 - 8)] = (_Float16)(d[reg] + bias);
      }
    } else {
      const int vch = ch0 - 16;
      union { unsigned u[2]; short4_t s; } pk;
      pk.u[0] = pack_bf16_2(d[0] + bias, d[1] + bias);
      pk.u[1] = pack_bf16_2(d[2] + bias, d[3] + bias);
      *(short4_t*)(vT + vbase_out + (size_t)vch * 32) = pk.s;
    }
  }
}

// ---------------------------------------------------------------------------
// Kernel 2 (v15): R14's 64-query / 16-wave structure, compiled under the
// EMPIRICAL launch-bounds law: VGPR cap ~= 256 / (2nd arg), independent of
// block size ((512,8)->32, (512,6)->40, (512,4)->64, (512,2)->88-at-128,
// (1024,4)->64+spill). (1024,2): cap 128 -> the kernel's natural 88 VGPRs
// fit, 16-wave block resident at 4 waves/SIMD (4x88=352 <= 512-reg file).
// Wave w covers keys [w*256, +256); ping-pong register prefetch; combine =
// 15 partials through 65,280 B LDS.
// ---------------------------------------------------------------------------
__global__ __launch_bounds__(1024, 2) void attn_kernel(
    const _Float16* __restrict__ fh,        // [B][N][8] f16, key-permuted slots
    const _Float16* __restrict__ gh,        // [B][N][8] f16 (x log2e)
    const unsigned short* __restrict__ vT,  // [b][kblock][ch][r] bf16
    float* __restrict__ out)                // [B][N][64] f32
{
  const int N    = 4096;
  const int lane = threadIdx.x & 63;
  const int w    = threadIdx.x >> 6;       // 0..15 = key range
  const int quad = lane >> 4;
  const int l15  = lane & 15;

  __shared__ float red[15][64][17];        // 65,280 B

  const int xcd = blockIdx.x & 7;
  const int b   = xcd >> 1;
  const int qg  = ((blockIdx.x >> 3) << 1) + (xcd & 1);  // 0..63
  const int q0  = qg * 64;
  const int kbase = w * 256;

  const _Float16* fbase = fh + (size_t)b * N * 8;
  const _Float16* gbase = gh + (size_t)b * N * 8;
  const short*    vbat  = (const short*)vT + (size_t)b * 262144 + (l15 << 5) + (quad << 3);

  half8_t gfrag[4] = {{}, {}, {}, {}};
  if (quad == 0) {
#pragma unroll
    for (int tt = 0; tt < 4; tt++)
      gfrag[tt] = *(const half8_t*)(gbase + (size_t)(q0 + tt * 16 + l15) * 8);
  }

  const f32x4 zc = {0.f, 0.f, 0.f, 0.f};
  f32x4 acc[4][4];
  f32x4 acc4[4];
#pragma unroll
  for (int tt = 0; tt < 4; tt++) {
    acc4[tt] = zc;
#pragma unroll
    for (int ct = 0; ct < 4; ct++) acc[tt][ct] = zc;
  }

  short8_t ones8;
#pragma unroll
  for (int i = 0; i < 8; i++) ones8[i] = (short)0x3F80;

  // ping-pong load buffers
  half8_t  fa0 = {}, fa1 = {}, fb0 = {}, fb1 = {};
  short8_t va0, va1, va2, va3, vb0, vb1, vb2, vb3;

  {
    const int k0 = kbase;
    if (quad == 0) {
      fa0 = *(const half8_t*)(fbase + (size_t)(k0 + l15) * 8);
      fa1 = *(const half8_t*)(fbase + (size_t)(k0 + 16 + l15) * 8);
    }
    const short* vk = vbat + ((size_t)(k0 >> 5) << 11);
    va0 = *(const short8_t*)(vk);
    va1 = *(const short8_t*)(vk + 512);
    va2 = *(const short8_t*)(vk + 1024);
    va3 = *(const short8_t*)(vk + 1536);
  }

  auto compute4 = [&](const half8_t& f0, const half8_t& f1,
                      const short8_t& v0, const short8_t& v1,
                      const short8_t& v2, const short8_t& v3) {
#pragma unroll
    for (int tt = 0; tt < 4; tt++) {
      f32x4 s0 = __builtin_amdgcn_mfma_f32_16x16x32_f16(f0, gfrag[tt], zc, 0, 0, 0);
      f32x4 s1 = __builtin_amdgcn_mfma_f32_16x16x32_f16(f1, gfrag[tt], zc, 0, 0, 0);
      float p00 = __builtin_amdgcn_exp2f(s0[0]), p01 = __builtin_amdgcn_exp2f(s0[1]);
      float p02 = __builtin_amdgcn_exp2f(s0[2]), p03 = __builtin_amdgcn_exp2f(s0[3]);
      float p10 = __builtin_amdgcn_exp2f(s1[0]), p11 = __builtin_amdgcn_exp2f(s1[1]);
      float p12 = __builtin_amdgcn_exp2f(s1[2]), p13 = __builtin_amdgcn_exp2f(s1[3]);
      union { unsigned u[4]; short8_t v; } pu;
      pu.u[0] = pack_bf16_2(p00, p01);
      pu.u[1] = pack_bf16_2(p02, p03);
      pu.u[2] = pack_bf16_2(p10, p11);
      pu.u[3] = pack_bf16_2(p12, p13);
      short8_t pfrag = pu.v;
      acc[tt][0] = __builtin_amdgcn_mfma_f32_16x16x32_bf16(v0, pfrag, acc[tt][0], 0, 0, 0);
      acc[tt][1] = __builtin_amdgcn_mfma_f32_16x16x32_bf16(v1, pfrag, acc[tt][1], 0, 0, 0);
      acc[tt][2] = __builtin_amdgcn_mfma_f32_16x16x32_bf16(v2, pfrag, acc[tt][2], 0, 0, 0);
      acc[tt][3] = __builtin_amdgcn_mfma_f32_16x16x32_bf16(v3, pfrag, acc[tt][3], 0, 0, 0);
      acc4[tt]   = __builtin_amdgcn_mfma_f32_16x16x32_bf16(ones8, pfrag, acc4[tt], 0, 0, 0);
    }
  };

#pragma unroll 1
  for (int cc = 0; cc < 8; cc += 2) {
    {
      const int k1 = kbase + (cc + 1) * 32;
      if (quad == 0) {
        fb0 = *(const half8_t*)(fbase + (size_t)(k1 + l15) * 8);
        fb1 = *(const half8_t*)(fbase + (size_t)(k1 + 16 + l15) * 8);
      }
      const short* vk = vbat + ((size_t)(k1 >> 5) << 11);
      vb0 = *(const short8_t*)(vk);
      vb1 = *(const short8_t*)(vk + 512);
      vb2 = *(const short8_t*)(vk + 1024);
      vb3 = *(const short8_t*)(vk + 1536);
    }
    compute4(fa0, fa1, va0, va1, va2, va3);
    if (cc + 2 < 8) {
      const int k2 = kbase + (cc + 2) * 32;
      if (quad == 0) {
        fa0 = *(const half8_t*)(fbase + (size_t)(k2 + l15) * 8);
        fa1 = *(const half8_t*)(fbase + (size_t)(k2 + 16 + l15) * 8);
      }
      const short* vk = vbat + ((size_t)(k2 >> 5) << 11);
      va0 = *(const short8_t*)(vk);
      va1 = *(const short8_t*)(vk + 512);
      va2 = *(const short8_t*)(vk + 1024);
      va3 = *(const short8_t*)(vk + 1536);
    }
    compute4(fb0, fb1, vb0, vb1, vb2, vb3);
  }

  // ---- cross-wave combine: 4 sequential phases, 15 partials each ----
#pragma unroll 1
  for (int tt = 0; tt < 4; tt++) {
    if (w > 0) {
      float* p = &red[w - 1][lane][0];
#pragma unroll
      for (int ct = 0; ct < 4; ct++)
#pragma unroll
        for (int reg = 0; reg < 4; reg++) p[ct * 4 + reg] = acc[tt][ct][reg];
      p[16] = acc4[tt][0];
    }
    __syncthreads();
    if (w == 0) {
      f32x4 a0 = acc[tt][0], a1 = acc[tt][1], a2 = acc[tt][2], a3 = acc[tt][3];
      float lv = acc4[tt][0];
#pragma unroll
      for (int ww = 0; ww < 15; ww++) {
        const float* p = &red[ww][lane][0];
#pragma unroll
        for (int reg = 0; reg < 4; reg++) {
          a0[reg] += p[0 + reg];
          a1[reg] += p[4 + reg];
          a2[reg] += p[8 + reg];
          a3[reg] += p[12 + reg];
        }
        lv += p[16];
      }
      const float inv = 1.0f / lv;
      float* ob = out + ((size_t)b * N + q0 + tt * 16 + l15) * 64 + (quad << 2);
      *(f32x4*)(ob)      = a0 * inv;
      *(f32x4*)(ob + 16) = a1 * inv;
      *(f32x4*)(ob + 32) = a2 * inv;
      *(f32x4*)(ob + 48) = a3 * inv;
    }
    __syncthreads();
  }
}

// ---------------------------------------------------------------------------
extern "C" void kernel_launch(void* const* d_in, const int* in_sizes, int n_in,
                              void* d_out, int out_size, void* d_ws, size_t ws_size,
                              hipStream_t stream) {
  const float* x  = (const float*)d_in[0];
  const float* Wf = (const float*)d_in[1];
  const float* bf = (const float*)d_in[2];
  const float* Wg = (const float*)d_in[3];
  const float* bg = (const float*)d_in[4];
  const float* Wh = (const float*)d_in[5];
  const float* bh = (const float*)d_in[6];
  float* out = (float*)d_out;

  char* ws = (char*)d_ws;
  _Float16* fh = (_Float16*)ws;                        // 256 KB
  _Float16* gh = (_Float16*)(ws + 262144);             // 256 KB
  unsigned short* vT = (unsigned short*)(ws + 524288); // 2 MB

  prep_kernel<<<256, 256, 0, stream>>>(x, Wf, bf, Wg, bg, Wh, bh, fh, gh, vT);
  attn_kernel<<<256, 1024, 0, stream>>>(fh, gh, vT, out);
}

// Round 16
// 185.745 us; speedup vs baseline: 1.0123x; 1.0100x over previous
//
#include <hip/hip_runtime.h>
#include <hip/hip_bf16.h>
#include <hip/hip_fp16.h>

typedef _Float16 half8_t  __attribute__((ext_vector_type(8)));
typedef short    short8_t __attribute__((ext_vector_type(8)));
typedef short    short4_t __attribute__((ext_vector_type(4)));
typedef float    f32x4    __attribute__((ext_vector_type(4)));

#define LOG2E 1.44269504088896f

__device__ __forceinline__ unsigned pack_bf16_2(float lo, float hi) {
  float2 f2; f2.x = lo; f2.y = hi;
  __hip_bfloat162 h2 = __float22bfloat162_rn(f2);
  return *reinterpret_cast<unsigned*>(&h2);
}

// ---------------------------------------------------------------------------
// Kernel 1 (v8, unchanged): MFMA prep. One block = 64 positions.
// C = x[64 x 64] @ W[64 x 80] via 16x16x32 f16 MFMA; epilogue writes f
// (key-permuted slots), g (x log2e), vT4 ([b][kblock][ch][r] bf16).
// ---------------------------------------------------------------------------
__global__ __launch_bounds__(256) void prep_kernel(
    const float* __restrict__ x,
    const float* __restrict__ Wf, const float* __restrict__ bf,
    const float* __restrict__ Wg, const float* __restrict__ bg,
    const float* __restrict__ Wh, const float* __restrict__ bh,
    _Float16* __restrict__ fh, _Float16* __restrict__ gh,
    unsigned short* __restrict__ vT)
{
  __shared__ _Float16 WtT[80 * 72];   // [ch][c], stride 72
  __shared__ float ball[80];
  const int t = threadIdx.x;

  for (int i = t; i < 512; i += 256) {
    int c = i >> 3, d = i & 7;
    WtT[d * 72 + c]       = (_Float16)Wf[i];
    WtT[(8 + d) * 72 + c] = (_Float16)(Wg[i] * LOG2E);
  }
  for (int i = t; i < 4096; i += 256) {
    int c = i >> 6, ch = i & 63;
    WtT[(16 + ch) * 72 + c] = (_Float16)Wh[i];
  }
  if (t < 80) ball[t] = (t < 8) ? bf[t] : (t < 16) ? bg[t - 8] * LOG2E : bh[t - 16];
  __syncthreads();

  const int lane = t & 63, w = t >> 6;
  const int quad = lane >> 4, l15 = lane & 15;
  const int p0 = blockIdx.x * 64;
  const int row = p0 + w * 16 + l15;

  const float* xr = x + (size_t)row * 64 + quad * 8;
  float4 xa = *(const float4*)(xr);
  float4 xb = *(const float4*)(xr + 4);
  float4 xc = *(const float4*)(xr + 32);
  float4 xd = *(const float4*)(xr + 36);
  half8_t a0, a1;
  a0[0]=(_Float16)xa.x; a0[1]=(_Float16)xa.y; a0[2]=(_Float16)xa.z; a0[3]=(_Float16)xa.w;
  a0[4]=(_Float16)xb.x; a0[5]=(_Float16)xb.y; a0[6]=(_Float16)xb.z; a0[7]=(_Float16)xb.w;
  a1[0]=(_Float16)xc.x; a1[1]=(_Float16)xc.y; a1[2]=(_Float16)xc.z; a1[3]=(_Float16)xc.w;
  a1[4]=(_Float16)xd.x; a1[5]=(_Float16)xd.y; a1[6]=(_Float16)xd.z; a1[7]=(_Float16)xd.w;

  const f32x4 zc = {0.f, 0.f, 0.f, 0.f};
  const int b     = p0 >> 12;
  const int nbase = (p0 & 4095) + w * 16 + quad * 4;
  const int kblock = nbase >> 5;
  const int r0     = nbase & 31;
  const int q8 = r0 >> 3, j8 = r0 & 7;
  const int slot0 = (j8 < 4) ? (q8 * 4 + j8) : (16 + q8 * 4 + (j8 - 4));
  const size_t fbase_out = ((size_t)b * 4096 + (kblock << 5) + slot0) * 8;
  const size_t gbase_out = ((size_t)p0 + w * 16 + quad * 4) * 8;
  const size_t vbase_out = (((size_t)b * 128 + kblock) << 11) + r0;

#pragma unroll
  for (int nt = 0; nt < 5; nt++) {
    const int ch0 = nt * 16 + l15;
    const _Float16* wt = &WtT[ch0 * 72 + quad * 8];
    half8_t b0 = *(const half8_t*)(wt);
    half8_t b1 = *(const half8_t*)(wt + 32);
    f32x4 d = __builtin_amdgcn_mfma_f32_16x16x32_f16(a0, b0, zc, 0, 0, 0);
    d = __builtin_amdgcn_mfma_f32_16x16x32_f16(a1, b1, d, 0, 0, 0);
    const float bias = ball[ch0];
    if (nt == 0) {
      if (l15 < 8) {
#pragma unroll
        for (int reg = 0; reg < 4; reg++)
          fh[fbase_out + (size_t)reg * 8 + l15] = (_Float16)(d[reg] + bias);
      } else {
#pragma unroll
        for (int reg = 0; reg < 4; reg++)
          gh[gbase_out + (size_t)reg * 8 + (l15 - 8)] = (_Float16)(d[reg] + bias);
      }
    } else {
      const int vch = ch0 - 16;
      union { unsigned u[2]; short4_t s; } pk;
      pk.u[0] = pack_bf16_2(d[0] + bias, d[1] + bias);
      pk.u[1] = pack_bf16_2(d[2] + bias, d[3] + bias);
      *(short4_t*)(vT + vbase_out + (size_t)vch * 32) = pk.s;
    }
  }
}

// ---------------------------------------------------------------------------
// Kernel 2 (v16): R14/R15 structure under the CORRECTED launch-bounds law:
// VGPR cap ~= 512 / waves-per-SIMD, where waves/SIMD = block_waves*arg/4.
//   (512,4)=8/SIMD->64; (512,2)=4/SIMD->128(fit 88); (1024,2)=8/SIMD->64
//   (spilled, R14/R15 — "256/arg" was a 512-thread coincidence).
// (1024,1): 16 waves/CU = 4/SIMD -> cap 128 -> natural 88 VGPRs fit,
// 4x88=352 <= 512-reg file. 64-query blocks, wave w = 256 keys, ping-pong
// prefetch, combine = 15 partials through 65,280 B LDS.
// ---------------------------------------------------------------------------
__global__ __launch_bounds__(1024, 1) void attn_kernel(
    const _Float16* __restrict__ fh,        // [B][N][8] f16, key-permuted slots
    const _Float16* __restrict__ gh,        // [B][N][8] f16 (x log2e)
    const unsigned short* __restrict__ vT,  // [b][kblock][ch][r] bf16
    float* __restrict__ out)                // [B][N][64] f32
{
  const int N    = 4096;
  const int lane = threadIdx.x & 63;
  const int w    = threadIdx.x >> 6;       // 0..15 = key range
  const int quad = lane >> 4;
  const int l15  = lane & 15;

  __shared__ float red[15][64][17];        // 65,280 B

  const int xcd = blockIdx.x & 7;
  const int b   = xcd >> 1;
  const int qg  = ((blockIdx.x >> 3) << 1) + (xcd & 1);  // 0..63
  const int q0  = qg * 64;
  const int kbase = w * 256;

  const _Float16* fbase = fh + (size_t)b * N * 8;
  const _Float16* gbase = gh + (size_t)b * N * 8;
  const short*    vbat  = (const short*)vT + (size_t)b * 262144 + (l15 << 5) + (quad << 3);

  half8_t gfrag[4] = {{}, {}, {}, {}};
  if (quad == 0) {
#pragma unroll
    for (int tt = 0; tt < 4; tt++)
      gfrag[tt] = *(const half8_t*)(gbase + (size_t)(q0 + tt * 16 + l15) * 8);
  }

  const f32x4 zc = {0.f, 0.f, 0.f, 0.f};
  f32x4 acc[4][4];
  f32x4 acc4[4];
#pragma unroll
  for (int tt = 0; tt < 4; tt++) {
    acc4[tt] = zc;
#pragma unroll
    for (int ct = 0; ct < 4; ct++) acc[tt][ct] = zc;
  }

  short8_t ones8;
#pragma unroll
  for (int i = 0; i < 8; i++) ones8[i] = (short)0x3F80;

  // ping-pong load buffers
  half8_t  fa0 = {}, fa1 = {}, fb0 = {}, fb1 = {};
  short8_t va0, va1, va2, va3, vb0, vb1, vb2, vb3;

  {
    const int k0 = kbase;
    if (quad == 0) {
      fa0 = *(const half8_t*)(fbase + (size_t)(k0 + l15) * 8);
      fa1 = *(const half8_t*)(fbase + (size_t)(k0 + 16 + l15) * 8);
    }
    const short* vk = vbat + ((size_t)(k0 >> 5) << 11);
    va0 = *(const short8_t*)(vk);
    va1 = *(const short8_t*)(vk + 512);
    va2 = *(const short8_t*)(vk + 1024);
    va3 = *(const short8_t*)(vk + 1536);
  }

  auto compute4 = [&](const half8_t& f0, const half8_t& f1,
                      const short8_t& v0, const short8_t& v1,
                      const short8_t& v2, const short8_t& v3) {
#pragma unroll
    for (int tt = 0; tt < 4; tt++) {
      f32x4 s0 = __builtin_amdgcn_mfma_f32_16x16x32_f16(f0, gfrag[tt], zc, 0, 0, 0);
      f32x4 s1 = __builtin_amdgcn_mfma_f32_16x16x32_f16(f1, gfrag[tt], zc, 0, 0, 0);
      float p00 = __builtin_amdgcn_exp2f(s0[0]), p01 = __builtin_amdgcn_exp2f(s0[1]);
      float p02 = __builtin_amdgcn_exp2f(s0[2]), p03 = __builtin_amdgcn_exp2f(s0[3]);
      float p10 = __builtin_amdgcn_exp2f(s1[0]), p11 = __builtin_amdgcn_exp2f(s1[1]);
      float p12 = __builtin_amdgcn_exp2f(s1[2]), p13 = __builtin_amdgcn_exp2f(s1[3]);
      union { unsigned u[4]; short8_t v; } pu;
      pu.u[0] = pack_bf16_2(p00, p01);
      pu.u[1] = pack_bf16_2(p02, p03);
      pu.u[2] = pack_bf16_2(p10, p11);
      pu.u[3] = pack_bf16_2(p12, p13);
      short8_t pfrag = pu.v;
      acc[tt][0] = __builtin_amdgcn_mfma_f32_16x16x32_bf16(v0, pfrag, acc[tt][0], 0, 0, 0);
      acc[tt][1] = __builtin_amdgcn_mfma_f32_16x16x32_bf16(v1, pfrag, acc[tt][1], 0, 0, 0);
      acc[tt][2] = __builtin_amdgcn_mfma_f32_16x16x32_bf16(v2, pfrag, acc[tt][2], 0, 0, 0);
      acc[tt][3] = __builtin_amdgcn_mfma_f32_16x16x32_bf16(v3, pfrag, acc[tt][3], 0, 0, 0);
      acc4[tt]   = __builtin_amdgcn_mfma_f32_16x16x32_bf16(ones8, pfrag, acc4[tt], 0, 0, 0);
    }
  };

#pragma unroll 1
  for (int cc = 0; cc < 8; cc += 2) {
    {
      const int k1 = kbase + (cc + 1) * 32;
      if (quad == 0) {
        fb0 = *(const half8_t*)(fbase + (size_t)(k1 + l15) * 8);
        fb1 = *(const half8_t*)(fbase + (size_t)(k1 + 16 + l15) * 8);
      }
      const short* vk = vbat + ((size_t)(k1 >> 5) << 11);
      vb0 = *(const short8_t*)(vk);
      vb1 = *(const short8_t*)(vk + 512);
      vb2 = *(const short8_t*)(vk + 1024);
      vb3 = *(const short8_t*)(vk + 1536);
    }
    compute4(fa0, fa1, va0, va1, va2, va3);
    if (cc + 2 < 8) {
      const int k2 = kbase + (cc + 2) * 32;
      if (quad == 0) {
        fa0 = *(const half8_t*)(fbase + (size_t)(k2 + l15) * 8);
        fa1 = *(const half8_t*)(fbase + (size_t)(k2 + 16 + l15) * 8);
      }
      const short* vk = vbat + ((size_t)(k2 >> 5) << 11);
      va0 = *(const short8_t*)(vk);
      va1 = *(const short8_t*)(vk + 512);
      va2 = *(const short8_t*)(vk + 1024);
      va3 = *(const short8_t*)(vk + 1536);
    }
    compute4(fb0, fb1, vb0, vb1, vb2, vb3);
  }

  // ---- cross-wave combine: 4 sequential phases, 15 partials each ----
#pragma unroll 1
  for (int tt = 0; tt < 4; tt++) {
    if (w > 0) {
      float* p = &red[w - 1][lane][0];
#pragma unroll
      for (int ct = 0; ct < 4; ct++)
#pragma unroll
        for (int reg = 0; reg < 4; reg++) p[ct * 4 + reg] = acc[tt][ct][reg];
      p[16] = acc4[tt][0];
    }
    __syncthreads();
    if (w == 0) {
      f32x4 a0 = acc[tt][0], a1 = acc[tt][1], a2 = acc[tt][2], a3 = acc[tt][3];
      float lv = acc4[tt][0];
#pragma unroll
      for (int ww = 0; ww < 15; ww++) {
        const float* p = &red[ww][lane][0];
#pragma unroll
        for (int reg = 0; reg < 4; reg++) {
          a0[reg] += p[0 + reg];
          a1[reg] += p[4 + reg];
          a2[reg] += p[8 + reg];
          a3[reg] += p[12 + reg];
        }
        lv += p[16];
      }
      const float inv = 1.0f / lv;
      float* ob = out + ((size_t)b * N + q0 + tt * 16 + l15) * 64 + (quad << 2);
      *(f32x4*)(ob)      = a0 * inv;
      *(f32x4*)(ob + 16) = a1 * inv;
      *(f32x4*)(ob + 32) = a2 * inv;
      *(f32x4*)(ob + 48) = a3 * inv;
    }
    __syncthreads();
  }
}

// ---------------------------------------------------------------------------
extern "C" void kernel_launch(void* const* d_in, const int* in_sizes, int n_in,
                              void* d_out, int out_size, void* d_ws, size_t ws_size,
                              hipStream_t stream) {
  const float* x  = (const float*)d_in[0];
  const float* Wf = (const float*)d_in[1];
  const float* bf = (const float*)d_in[2];
  const float* Wg = (const float*)d_in[3];
  const float* bg = (const float*)d_in[4];
  const float* Wh = (const float*)d_in[5];
  const float* bh = (const float*)d_in[6];
  float* out = (float*)d_out;

  char* ws = (char*)d_ws;
  _Float16* fh = (_Float16*)ws;                        // 256 KB
  _Float16* gh = (_Float16*)(ws + 262144);             // 256 KB
  unsigned short* vT = (unsigned short*)(ws + 524288); // 2 MB

  prep_kernel<<<256, 256, 0, stream>>>(x, Wf, bf, Wg, bg, Wh, bh, fh, gh, vT);
  attn_kernel<<<256, 1024, 0, stream>>>(fh, gh, vT, out);
}

// Round 17
// 110.078 us; speedup vs baseline: 1.7082x; 1.6874x over previous
//
#include <hip/hip_runtime.h>
#include <hip/hip_bf16.h>
#include <hip/hip_fp16.h>

typedef _Float16 half8_t  __attribute__((ext_vector_type(8)));
typedef short    short8_t __attribute__((ext_vector_type(8)));
typedef short    short4_t __attribute__((ext_vector_type(4)));
typedef float    f32x4    __attribute__((ext_vector_type(4)));

#define LOG2E 1.44269504088896f

__device__ __forceinline__ unsigned pack_bf16_2(float lo, float hi) {
  float2 f2; f2.x = lo; f2.y = hi;
  __hip_bfloat162 h2 = __float22bfloat162_rn(f2);
  return *reinterpret_cast<unsigned*>(&h2);
}

// ---------------------------------------------------------------------------
// Kernel 1 (v8, unchanged): MFMA prep. One block = 64 positions.
// C = x[64 x 64] @ W[64 x 80] via 16x16x32 f16 MFMA; epilogue writes f
// (key-permuted slots), g (x log2e), vT4 ([b][kblock][ch][r] bf16).
// ---------------------------------------------------------------------------
__global__ __launch_bounds__(256) void prep_kernel(
    const float* __restrict__ x,
    const float* __restrict__ Wf, const float* __restrict__ bf,
    const float* __restrict__ Wg, const float* __restrict__ bg,
    const float* __restrict__ Wh, const float* __restrict__ bh,
    _Float16* __restrict__ fh, _Float16* __restrict__ gh,
    unsigned short* __restrict__ vT)
{
  __shared__ _Float16 WtT[80 * 72];   // [ch][c], stride 72
  __shared__ float ball[80];
  const int t = threadIdx.x;

  for (int i = t; i < 512; i += 256) {
    int c = i >> 3, d = i & 7;
    WtT[d * 72 + c]       = (_Float16)Wf[i];
    WtT[(8 + d) * 72 + c] = (_Float16)(Wg[i] * LOG2E);
  }
  for (int i = t; i < 4096; i += 256) {
    int c = i >> 6, ch = i & 63;
    WtT[(16 + ch) * 72 + c] = (_Float16)Wh[i];
  }
  if (t < 80) ball[t] = (t < 8) ? bf[t] : (t < 16) ? bg[t - 8] * LOG2E : bh[t - 16];
  __syncthreads();

  const int lane = t & 63, w = t >> 6;
  const int quad = lane >> 4, l15 = lane & 15;
  const int p0 = blockIdx.x * 64;
  const int row = p0 + w * 16 + l15;

  const float* xr = x + (size_t)row * 64 + quad * 8;
  float4 xa = *(const float4*)(xr);
  float4 xb = *(const float4*)(xr + 4);
  float4 xc = *(const float4*)(xr + 32);
  float4 xd = *(const float4*)(xr + 36);
  half8_t a0, a1;
  a0[0]=(_Float16)xa.x; a0[1]=(_Float16)xa.y; a0[2]=(_Float16)xa.z; a0[3]=(_Float16)xa.w;
  a0[4]=(_Float16)xb.x; a0[5]=(_Float16)xb.y; a0[6]=(_Float16)xb.z; a0[7]=(_Float16)xb.w;
  a1[0]=(_Float16)xc.x; a1[1]=(_Float16)xc.y; a1[2]=(_Float16)xc.z; a1[3]=(_Float16)xc.w;
  a1[4]=(_Float16)xd.x; a1[5]=(_Float16)xd.y; a1[6]=(_Float16)xd.z; a1[7]=(_Float16)xd.w;

  const f32x4 zc = {0.f, 0.f, 0.f, 0.f};
  const int b     = p0 >> 12;
  const int nbase = (p0 & 4095) + w * 16 + quad * 4;
  const int kblock = nbase >> 5;
  const int r0     = nbase & 31;
  const int q8 = r0 >> 3, j8 = r0 & 7;
  const int slot0 = (j8 < 4) ? (q8 * 4 + j8) : (16 + q8 * 4 + (j8 - 4));
  const size_t fbase_out = ((size_t)b * 4096 + (kblock << 5) + slot0) * 8;
  const size_t gbase_out = ((size_t)p0 + w * 16 + quad * 4) * 8;
  const size_t vbase_out = (((size_t)b * 128 + kblock) << 11) + r0;

#pragma unroll
  for (int nt = 0; nt < 5; nt++) {
    const int ch0 = nt * 16 + l15;
    const _Float16* wt = &WtT[ch0 * 72 + quad * 8];
    half8_t b0 = *(const half8_t*)(wt);
    half8_t b1 = *(const half8_t*)(wt + 32);
    f32x4 d = __builtin_amdgcn_mfma_f32_16x16x32_f16(a0, b0, zc, 0, 0, 0);
    d = __builtin_amdgcn_mfma_f32_16x16x32_f16(a1, b1, d, 0, 0, 0);
    const float bias = ball[ch0];
    if (nt == 0) {
      if (l15 < 8) {
#pragma unroll
        for (int reg = 0; reg < 4; reg++)
          fh[fbase_out + (size_t)reg * 8 + l15] = (_Float16)(d[reg] + bias);
      } else {
#pragma unroll
        for (int reg = 0; reg < 4; reg++)
          gh[gbase_out + (size_t)reg * 8 + (l15 - 8)] = (_Float16)(d[reg] + bias);
      }
    } else {
      const int vch = ch0 - 16;
      union { unsigned u[2]; short4_t s; } pk;
      pk.u[0] = pack_bf16_2(d[0] + bias, d[1] + bias);
      pk.u[1] = pack_bf16_2(d[2] + bias, d[3] + bias);
      *(short4_t*)(vT + vbase_out + (size_t)vch * 32) = pk.s;
    }
  }
}

// ---------------------------------------------------------------------------
// Kernel 2 (v17): 32-query blocks x 8 waves under the FINAL launch-bounds
// law: 1024-thr blocks hard-cap at 64 VGPR (R14/R15/R16 all spilled — 16-wave
// blocks condemned); (512,2) grants cap 128 which fits this kernel's ~110.
// Grid 512 = 2 blocks/CU = 4 waves/SIMD (4 x ~112 = 448 <= 512-reg file;
// LDS 30.5KB x 2 = 61KB <= 160KB). Same verified machinery: key-permuted
// shuffle-free scores, direct-B PV, ones-A denominator, ping-pong prefetch.
// Wave w covers keys [w*512, +512); 2 q-tiles share every f/vT load.
// ---------------------------------------------------------------------------
__global__ __launch_bounds__(512, 2) void attn_kernel(
    const _Float16* __restrict__ fh,        // [B][N][8] f16, key-permuted slots
    const _Float16* __restrict__ gh,        // [B][N][8] f16 (x log2e)
    const unsigned short* __restrict__ vT,  // [b][kblock][ch][r] bf16
    float* __restrict__ out)                // [B][N][64] f32
{
  const int N    = 4096;
  const int lane = threadIdx.x & 63;
  const int w    = threadIdx.x >> 6;       // 0..7 = key range
  const int quad = lane >> 4;
  const int l15  = lane & 15;

  __shared__ float red[7][64][17];         // 30,464 B; reused for 2 phases

  const int xcd = blockIdx.x & 7;
  const int b   = xcd >> 1;
  const int qg  = ((blockIdx.x >> 3) << 1) + (xcd & 1);  // 0..127
  const int q0  = qg * 32;
  const int kbase = w * 512;

  const _Float16* fbase = fh + (size_t)b * N * 8;
  const _Float16* gbase = gh + (size_t)b * N * 8;
  const short*    vbat  = (const short*)vT + (size_t)b * 262144 + (l15 << 5) + (quad << 3);

  half8_t gfrag[2] = {{}, {}};
  if (quad == 0) {
#pragma unroll
    for (int tt = 0; tt < 2; tt++)
      gfrag[tt] = *(const half8_t*)(gbase + (size_t)(q0 + tt * 16 + l15) * 8);
  }

  const f32x4 zc = {0.f, 0.f, 0.f, 0.f};
  f32x4 acc[2][4];
  f32x4 acc4[2];
#pragma unroll
  for (int tt = 0; tt < 2; tt++) {
    acc4[tt] = zc;
#pragma unroll
    for (int ct = 0; ct < 4; ct++) acc[tt][ct] = zc;
  }

  short8_t ones8;
#pragma unroll
  for (int i = 0; i < 8; i++) ones8[i] = (short)0x3F80;

  // ping-pong load buffers
  half8_t  fa0 = {}, fa1 = {}, fb0 = {}, fb1 = {};
  short8_t va0, va1, va2, va3, vb0, vb1, vb2, vb3;

  {
    const int k0 = kbase;
    if (quad == 0) {
      fa0 = *(const half8_t*)(fbase + (size_t)(k0 + l15) * 8);
      fa1 = *(const half8_t*)(fbase + (size_t)(k0 + 16 + l15) * 8);
    }
    const short* vk = vbat + ((size_t)(k0 >> 5) << 11);
    va0 = *(const short8_t*)(vk);
    va1 = *(const short8_t*)(vk + 512);
    va2 = *(const short8_t*)(vk + 1024);
    va3 = *(const short8_t*)(vk + 1536);
  }

  auto compute2 = [&](const half8_t& f0, const half8_t& f1,
                      const short8_t& v0, const short8_t& v1,
                      const short8_t& v2, const short8_t& v3) {
#pragma unroll
    for (int tt = 0; tt < 2; tt++) {
      f32x4 s0 = __builtin_amdgcn_mfma_f32_16x16x32_f16(f0, gfrag[tt], zc, 0, 0, 0);
      f32x4 s1 = __builtin_amdgcn_mfma_f32_16x16x32_f16(f1, gfrag[tt], zc, 0, 0, 0);
      float p00 = __builtin_amdgcn_exp2f(s0[0]), p01 = __builtin_amdgcn_exp2f(s0[1]);
      float p02 = __builtin_amdgcn_exp2f(s0[2]), p03 = __builtin_amdgcn_exp2f(s0[3]);
      float p10 = __builtin_amdgcn_exp2f(s1[0]), p11 = __builtin_amdgcn_exp2f(s1[1]);
      float p12 = __builtin_amdgcn_exp2f(s1[2]), p13 = __builtin_amdgcn_exp2f(s1[3]);
      union { unsigned u[4]; short8_t v; } pu;
      pu.u[0] = pack_bf16_2(p00, p01);
      pu.u[1] = pack_bf16_2(p02, p03);
      pu.u[2] = pack_bf16_2(p10, p11);
      pu.u[3] = pack_bf16_2(p12, p13);
      short8_t pfrag = pu.v;
      acc[tt][0] = __builtin_amdgcn_mfma_f32_16x16x32_bf16(v0, pfrag, acc[tt][0], 0, 0, 0);
      acc[tt][1] = __builtin_amdgcn_mfma_f32_16x16x32_bf16(v1, pfrag, acc[tt][1], 0, 0, 0);
      acc[tt][2] = __builtin_amdgcn_mfma_f32_16x16x32_bf16(v2, pfrag, acc[tt][2], 0, 0, 0);
      acc[tt][3] = __builtin_amdgcn_mfma_f32_16x16x32_bf16(v3, pfrag, acc[tt][3], 0, 0, 0);
      acc4[tt]   = __builtin_amdgcn_mfma_f32_16x16x32_bf16(ones8, pfrag, acc4[tt], 0, 0, 0);
    }
  };

#pragma unroll 1
  for (int cc = 0; cc < 16; cc += 2) {
    {
      const int k1 = kbase + (cc + 1) * 32;
      if (quad == 0) {
        fb0 = *(const half8_t*)(fbase + (size_t)(k1 + l15) * 8);
        fb1 = *(const half8_t*)(fbase + (size_t)(k1 + 16 + l15) * 8);
      }
      const short* vk = vbat + ((size_t)(k1 >> 5) << 11);
      vb0 = *(const short8_t*)(vk);
      vb1 = *(const short8_t*)(vk + 512);
      vb2 = *(const short8_t*)(vk + 1024);
      vb3 = *(const short8_t*)(vk + 1536);
    }
    compute2(fa0, fa1, va0, va1, va2, va3);
    if (cc + 2 < 16) {
      const int k2 = kbase + (cc + 2) * 32;
      if (quad == 0) {
        fa0 = *(const half8_t*)(fbase + (size_t)(k2 + l15) * 8);
        fa1 = *(const half8_t*)(fbase + (size_t)(k2 + 16 + l15) * 8);
      }
      const short* vk = vbat + ((size_t)(k2 >> 5) << 11);
      va0 = *(const short8_t*)(vk);
      va1 = *(const short8_t*)(vk + 512);
      va2 = *(const short8_t*)(vk + 1024);
      va3 = *(const short8_t*)(vk + 1536);
    }
    compute2(fb0, fb1, vb0, vb1, vb2, vb3);
  }

  // ---- cross-wave combine: 2 sequential phases ----
#pragma unroll 1
  for (int tt = 0; tt < 2; tt++) {
    if (w > 0) {
      float* p = &red[w - 1][lane][0];
#pragma unroll
      for (int ct = 0; ct < 4; ct++)
#pragma unroll
        for (int reg = 0; reg < 4; reg++) p[ct * 4 + reg] = acc[tt][ct][reg];
      p[16] = acc4[tt][0];
    }
    __syncthreads();
    if (w == 0) {
      f32x4 a0 = acc[tt][0], a1 = acc[tt][1], a2 = acc[tt][2], a3 = acc[tt][3];
      float lv = acc4[tt][0];
#pragma unroll
      for (int ww = 0; ww < 7; ww++) {
        const float* p = &red[ww][lane][0];
#pragma unroll
        for (int reg = 0; reg < 4; reg++) {
          a0[reg] += p[0 + reg];
          a1[reg] += p[4 + reg];
          a2[reg] += p[8 + reg];
          a3[reg] += p[12 + reg];
        }
        lv += p[16];
      }
      const float inv = 1.0f / lv;
      float* ob = out + ((size_t)b * N + q0 + tt * 16 + l15) * 64 + (quad << 2);
      *(f32x4*)(ob)      = a0 * inv;
      *(f32x4*)(ob + 16) = a1 * inv;
      *(f32x4*)(ob + 32) = a2 * inv;
      *(f32x4*)(ob + 48) = a3 * inv;
    }
    __syncthreads();
  }
}

// ---------------------------------------------------------------------------
extern "C" void kernel_launch(void* const* d_in, const int* in_sizes, int n_in,
                              void* d_out, int out_size, void* d_ws, size_t ws_size,
                              hipStream_t stream) {
  const float* x  = (const float*)d_in[0];
  const float* Wf = (const float*)d_in[1];
  const float* bf = (const float*)d_in[2];
  const float* Wg = (const float*)d_in[3];
  const float* bg = (const float*)d_in[4];
  const float* Wh = (const float*)d_in[5];
  const float* bh = (const float*)d_in[6];
  float* out = (float*)d_out;

  char* ws = (char*)d_ws;
  _Float16* fh = (_Float16*)ws;                        // 256 KB
  _Float16* gh = (_Float16*)(ws + 262144);             // 256 KB
  unsigned short* vT = (unsigned short*)(ws + 524288); // 2 MB

  prep_kernel<<<256, 256, 0, stream>>>(x, Wf, bf, Wg, bg, Wh, bh, fh, gh, vT);
  attn_kernel<<<512, 512, 0, stream>>>(fh, gh, vT, out);
}

// Round 18
// 102.968 us; speedup vs baseline: 1.8262x; 1.0690x over previous
//
#include <hip/hip_runtime.h>
#include <hip/hip_bf16.h>
#include <hip/hip_fp16.h>

typedef _Float16 half8_t  __attribute__((ext_vector_type(8)));
typedef short    short8_t __attribute__((ext_vector_type(8)));
typedef short    short4_t __attribute__((ext_vector_type(4)));
typedef float    f32x4    __attribute__((ext_vector_type(4)));

#define LOG2E 1.44269504088896f

__device__ __forceinline__ unsigned pack_bf16_2(float lo, float hi) {
  float2 f2; f2.x = lo; f2.y = hi;
  __hip_bfloat162 h2 = __float22bfloat162_rn(f2);
  return *reinterpret_cast<unsigned*>(&h2);
}

// ---------------------------------------------------------------------------
// Kernel 1 (v8): MFMA prep. One block = 64 positions; wave w = 16-pos m-tile.
// C = x[64 x 64] @ W[64 x 80] via 16x16x32 f16 MFMA (fp32 acc); W^T staged in
// LDS ([ch][c], stride 72 halves). Epilogue writes attn's exact layouts:
//   f  (ch 0-7):  key-permuted slots (slot = (j<4)? q8*4+j : 16+q8*4+j-4)
//   g  (ch 8-15): [pos][8], W/b pre-scaled by log2e
//   vT4(ch16-79): [b][kblock][ch][r] bf16
// ---------------------------------------------------------------------------
__global__ __launch_bounds__(256) void prep_kernel(
    const float* __restrict__ x,
    const float* __restrict__ Wf, const float* __restrict__ bf,
    const float* __restrict__ Wg, const float* __restrict__ bg,
    const float* __restrict__ Wh, const float* __restrict__ bh,
    _Float16* __restrict__ fh, _Float16* __restrict__ gh,
    unsigned short* __restrict__ vT)
{
  __shared__ _Float16 WtT[80 * 72];   // [ch][c], stride 72
  __shared__ float ball[80];
  const int t = threadIdx.x;

  for (int i = t; i < 512; i += 256) {
    int c = i >> 3, d = i & 7;
    WtT[d * 72 + c]       = (_Float16)Wf[i];
    WtT[(8 + d) * 72 + c] = (_Float16)(Wg[i] * LOG2E);
  }
  for (int i = t; i < 4096; i += 256) {
    int c = i >> 6, ch = i & 63;
    WtT[(16 + ch) * 72 + c] = (_Float16)Wh[i];
  }
  if (t < 80) ball[t] = (t < 8) ? bf[t] : (t < 16) ? bg[t - 8] * LOG2E : bh[t - 16];
  __syncthreads();

  const int lane = t & 63, w = t >> 6;
  const int quad = lane >> 4, l15 = lane & 15;
  const int p0 = blockIdx.x * 64;
  const int row = p0 + w * 16 + l15;

  const float* xr = x + (size_t)row * 64 + quad * 8;
  float4 xa = *(const float4*)(xr);
  float4 xb = *(const float4*)(xr + 4);
  float4 xc = *(const float4*)(xr + 32);
  float4 xd = *(const float4*)(xr + 36);
  half8_t a0, a1;
  a0[0]=(_Float16)xa.x; a0[1]=(_Float16)xa.y; a0[2]=(_Float16)xa.z; a0[3]=(_Float16)xa.w;
  a0[4]=(_Float16)xb.x; a0[5]=(_Float16)xb.y; a0[6]=(_Float16)xb.z; a0[7]=(_Float16)xb.w;
  a1[0]=(_Float16)xc.x; a1[1]=(_Float16)xc.y; a1[2]=(_Float16)xc.z; a1[3]=(_Float16)xc.w;
  a1[4]=(_Float16)xd.x; a1[5]=(_Float16)xd.y; a1[6]=(_Float16)xd.z; a1[7]=(_Float16)xd.w;

  const f32x4 zc = {0.f, 0.f, 0.f, 0.f};
  const int b     = p0 >> 12;
  const int nbase = (p0 & 4095) + w * 16 + quad * 4;
  const int kblock = nbase >> 5;
  const int r0     = nbase & 31;
  const int q8 = r0 >> 3, j8 = r0 & 7;
  const int slot0 = (j8 < 4) ? (q8 * 4 + j8) : (16 + q8 * 4 + (j8 - 4));
  const size_t fbase_out = ((size_t)b * 4096 + (kblock << 5) + slot0) * 8;
  const size_t gbase_out = ((size_t)p0 + w * 16 + quad * 4) * 8;
  const size_t vbase_out = (((size_t)b * 128 + kblock) << 11) + r0;

#pragma unroll
  for (int nt = 0; nt < 5; nt++) {
    const int ch0 = nt * 16 + l15;
    const _Float16* wt = &WtT[ch0 * 72 + quad * 8];
    half8_t b0 = *(const half8_t*)(wt);
    half8_t b1 = *(const half8_t*)(wt + 32);
    f32x4 d = __builtin_amdgcn_mfma_f32_16x16x32_f16(a0, b0, zc, 0, 0, 0);
    d = __builtin_amdgcn_mfma_f32_16x16x32_f16(a1, b1, d, 0, 0, 0);
    const float bias = ball[ch0];
    if (nt == 0) {
      if (l15 < 8) {
#pragma unroll
        for (int reg = 0; reg < 4; reg++)
          fh[fbase_out + (size_t)reg * 8 + l15] = (_Float16)(d[reg] + bias);
      } else {
#pragma unroll
        for (int reg = 0; reg < 4; reg++)
          gh[gbase_out + (size_t)reg * 8 + (l15 - 8)] = (_Float16)(d[reg] + bias);
      }
    } else {
      const int vch = ch0 - 16;
      union { unsigned u[2]; short4_t s; } pk;
      pk.u[0] = pack_bf16_2(d[0] + bias, d[1] + bias);
      pk.u[1] = pack_bf16_2(d[2] + bias, d[3] + bias);
      *(short4_t*)(vT + vbase_out + (size_t)vch * 32) = pk.s;
    }
  }
}

// ---------------------------------------------------------------------------
// Kernel 2 (v13 — proven best, R13 = 104.3 us total): 64-query blocks,
// 8 waves, shuffle-free flash attention. 256 blocks x 512 thr; block =
// (batch, 64 queries = 4 tiles); wave w covers keys [w*512, +512) and serves
// all 4 q-tiles from one set of f/vT loads (147 MB total key traffic).
// Key-permuted scores -> exp results ARE the PV B-frags (zero cross-lane
// ops); V^T A-frags contiguous; ones-A MFMA denominator; ping-pong register
// prefetch. (512,2): cap 128, natural 88 VGPRs, no spill.
// ---------------------------------------------------------------------------
__global__ __launch_bounds__(512, 2) void attn_kernel(
    const _Float16* __restrict__ fh,        // [B][N][8] f16, key-permuted slots
    const _Float16* __restrict__ gh,        // [B][N][8] f16 (x log2e)
    const unsigned short* __restrict__ vT,  // [b][kblock][ch][r] bf16
    float* __restrict__ out)                // [B][N][64] f32
{
  const int N    = 4096;
  const int lane = threadIdx.x & 63;
  const int w    = threadIdx.x >> 6;       // 0..7 = key range
  const int quad = lane >> 4;
  const int l15  = lane & 15;

  __shared__ float red[7][64][17];

  const int xcd = blockIdx.x & 7;
  const int b   = xcd >> 1;
  const int qg  = ((blockIdx.x >> 3) << 1) + (xcd & 1);  // 0..63
  const int q0  = qg * 64;
  const int kbase = w * 512;

  const _Float16* fbase = fh + (size_t)b * N * 8;
  const _Float16* gbase = gh + (size_t)b * N * 8;
  const short*    vbat  = (const short*)vT + (size_t)b * 262144 + (l15 << 5) + (quad << 3);

  half8_t gfrag[4] = {{}, {}, {}, {}};
  if (quad == 0) {
#pragma unroll
    for (int tt = 0; tt < 4; tt++)
      gfrag[tt] = *(const half8_t*)(gbase + (size_t)(q0 + tt * 16 + l15) * 8);
  }

  const f32x4 zc = {0.f, 0.f, 0.f, 0.f};
  f32x4 acc[4][4];
  f32x4 acc4[4];
#pragma unroll
  for (int tt = 0; tt < 4; tt++) {
    acc4[tt] = zc;
#pragma unroll
    for (int ct = 0; ct < 4; ct++) acc[tt][ct] = zc;
  }

  short8_t ones8;
#pragma unroll
  for (int i = 0; i < 8; i++) ones8[i] = (short)0x3F80;

  // ping-pong load buffers
  half8_t  fa0 = {}, fa1 = {}, fb0 = {}, fb1 = {};
  short8_t va0, va1, va2, va3, vb0, vb1, vb2, vb3;

  {
    const int k0 = kbase;
    if (quad == 0) {
      fa0 = *(const half8_t*)(fbase + (size_t)(k0 + l15) * 8);
      fa1 = *(const half8_t*)(fbase + (size_t)(k0 + 16 + l15) * 8);
    }
    const short* vk = vbat + ((size_t)(k0 >> 5) << 11);
    va0 = *(const short8_t*)(vk);
    va1 = *(const short8_t*)(vk + 512);
    va2 = *(const short8_t*)(vk + 1024);
    va3 = *(const short8_t*)(vk + 1536);
  }

  auto compute4 = [&](const half8_t& f0, const half8_t& f1,
                      const short8_t& v0, const short8_t& v1,
                      const short8_t& v2, const short8_t& v3) {
#pragma unroll
    for (int tt = 0; tt < 4; tt++) {
      f32x4 s0 = __builtin_amdgcn_mfma_f32_16x16x32_f16(f0, gfrag[tt], zc, 0, 0, 0);
      f32x4 s1 = __builtin_amdgcn_mfma_f32_16x16x32_f16(f1, gfrag[tt], zc, 0, 0, 0);
      float p00 = __builtin_amdgcn_exp2f(s0[0]), p01 = __builtin_amdgcn_exp2f(s0[1]);
      float p02 = __builtin_amdgcn_exp2f(s0[2]), p03 = __builtin_amdgcn_exp2f(s0[3]);
      float p10 = __builtin_amdgcn_exp2f(s1[0]), p11 = __builtin_amdgcn_exp2f(s1[1]);
      float p12 = __builtin_amdgcn_exp2f(s1[2]), p13 = __builtin_amdgcn_exp2f(s1[3]);
      union { unsigned u[4]; short8_t v; } pu;
      pu.u[0] = pack_bf16_2(p00, p01);
      pu.u[1] = pack_bf16_2(p02, p03);
      pu.u[2] = pack_bf16_2(p10, p11);
      pu.u[3] = pack_bf16_2(p12, p13);
      short8_t pfrag = pu.v;
      acc[tt][0] = __builtin_amdgcn_mfma_f32_16x16x32_bf16(v0, pfrag, acc[tt][0], 0, 0, 0);
      acc[tt][1] = __builtin_amdgcn_mfma_f32_16x16x32_bf16(v1, pfrag, acc[tt][1], 0, 0, 0);
      acc[tt][2] = __builtin_amdgcn_mfma_f32_16x16x32_bf16(v2, pfrag, acc[tt][2], 0, 0, 0);
      acc[tt][3] = __builtin_amdgcn_mfma_f32_16x16x32_bf16(v3, pfrag, acc[tt][3], 0, 0, 0);
      acc4[tt]   = __builtin_amdgcn_mfma_f32_16x16x32_bf16(ones8, pfrag, acc4[tt], 0, 0, 0);
    }
  };

#pragma unroll 1
  for (int cc = 0; cc < 16; cc += 2) {
    {
      const int k1 = kbase + (cc + 1) * 32;
      if (quad == 0) {
        fb0 = *(const half8_t*)(fbase + (size_t)(k1 + l15) * 8);
        fb1 = *(const half8_t*)(fbase + (size_t)(k1 + 16 + l15) * 8);
      }
      const short* vk = vbat + ((size_t)(k1 >> 5) << 11);
      vb0 = *(const short8_t*)(vk);
      vb1 = *(const short8_t*)(vk + 512);
      vb2 = *(const short8_t*)(vk + 1024);
      vb3 = *(const short8_t*)(vk + 1536);
    }
    compute4(fa0, fa1, va0, va1, va2, va3);
    if (cc + 2 < 16) {
      const int k2 = kbase + (cc + 2) * 32;
      if (quad == 0) {
        fa0 = *(const half8_t*)(fbase + (size_t)(k2 + l15) * 8);
        fa1 = *(const half8_t*)(fbase + (size_t)(k2 + 16 + l15) * 8);
      }
      const short* vk = vbat + ((size_t)(k2 >> 5) << 11);
      va0 = *(const short8_t*)(vk);
      va1 = *(const short8_t*)(vk + 512);
      va2 = *(const short8_t*)(vk + 1024);
      va3 = *(const short8_t*)(vk + 1536);
    }
    compute4(fb0, fb1, vb0, vb1, vb2, vb3);
  }

  // ---- cross-wave combine: 4 sequential phases, 7 partials each ----
#pragma unroll 1
  for (int tt = 0; tt < 4; tt++) {
    if (w > 0) {
      float* p = &red[w - 1][lane][0];
#pragma unroll
      for (int ct = 0; ct < 4; ct++)
#pragma unroll
        for (int reg = 0; reg < 4; reg++) p[ct * 4 + reg] = acc[tt][ct][reg];
      p[16] = acc4[tt][0];
    }
    __syncthreads();
    if (w == 0) {
      f32x4 a0 = acc[tt][0], a1 = acc[tt][1], a2 = acc[tt][2], a3 = acc[tt][3];
      float lv = acc4[tt][0];
#pragma unroll
      for (int ww = 0; ww < 7; ww++) {
        const float* p = &red[ww][lane][0];
#pragma unroll
        for (int reg = 0; reg < 4; reg++) {
          a0[reg] += p[0 + reg];
          a1[reg] += p[4 + reg];
          a2[reg] += p[8 + reg];
          a3[reg] += p[12 + reg];
        }
        lv += p[16];
      }
      const float inv = 1.0f / lv;
      float* ob = out + ((size_t)b * N + q0 + tt * 16 + l15) * 64 + (quad << 2);
      *(f32x4*)(ob)      = a0 * inv;
      *(f32x4*)(ob + 16) = a1 * inv;
      *(f32x4*)(ob + 32) = a2 * inv;
      *(f32x4*)(ob + 48) = a3 * inv;
    }
    __syncthreads();
  }
}

// ---------------------------------------------------------------------------
extern "C" void kernel_launch(void* const* d_in, const int* in_sizes, int n_in,
                              void* d_out, int out_size, void* d_ws, size_t ws_size,
                              hipStream_t stream) {
  const float* x  = (const float*)d_in[0];
  const float* Wf = (const float*)d_in[1];
  const float* bf = (const float*)d_in[2];
  const float* Wg = (const float*)d_in[3];
  const float* bg = (const float*)d_in[4];
  const float* Wh = (const float*)d_in[5];
  const float* bh = (const float*)d_in[6];
  float* out = (float*)d_out;

  char* ws = (char*)d_ws;
  _Float16* fh = (_Float16*)ws;                        // 256 KB
  _Float16* gh = (_Float16*)(ws + 262144);             // 256 KB
  unsigned short* vT = (unsigned short*)(ws + 524288); // 2 MB

  prep_kernel<<<256, 256, 0, stream>>>(x, Wf, bf, Wg, bg, Wh, bh, fh, gh, vT);
  attn_kernel<<<256, 512, 0, stream>>>(fh, gh, vT, out);
}